// Round 1
// baseline (4957.986 us; speedup 1.0000x reference)
//
#include <hip/hip_runtime.h>
#include <cstdint>

#define NU 100000
#define NI 100000
#define NN 200000
#define NE 3200000
#define TXT 768
#define DD 32
#define WT_S 772   // LDS row stride for W1^T (floats)

__device__ __forceinline__ float lrelu(float x) { return x >= 0.f ? x : 0.01f * x; }

// ---------------------------------------------------------------------------
// Copy pretrained 16-dim embeddings into ego[:,0:16] and out[:,0:16]
// ---------------------------------------------------------------------------
__global__ void copy_emb_kernel(const float* __restrict__ uemb,
                                const float* __restrict__ iemb,
                                float* __restrict__ ego,
                                float* __restrict__ outp)
{
    int idx = blockIdx.x * blockDim.x + threadIdx.x;  // over NN*4 float4s
    if (idx >= NN * 4) return;
    int n = idx >> 2, q = idx & 3;
    float4 v;
    if (n < NU) v = ((const float4*)uemb)[(size_t)n * 4 + q];
    else        v = ((const float4*)iemb)[(size_t)(n - NU) * 4 + q];
    ((float4*)ego)[(size_t)n * 8 + q]   = v;   // ego row: 32 floats = 8 float4
    ((float4*)outp)[(size_t)n * 32 + q] = v;   // out row: 128 floats = 32 float4
}

// ---------------------------------------------------------------------------
// created = relu(X @ W1) @ W2 ; writes ego[:,16:32] and out[:,16:32]
// Block: 256 threads. Thread (cg = t&7, r = t>>3): 4 cols of h, 1 row.
// W1^T staged in LDS with XOR swizzle (conflict-free across col-groups).
// Second matmul (32->16) reduced across the 8 col-groups via shfl_xor.
// ---------------------------------------------------------------------------
__global__ __launch_bounds__(256) void mlp_kernel(
    const float* __restrict__ X,    // nrows x 768
    const float* __restrict__ W1,   // 768 x 32
    const float* __restrict__ W2,   // 32 x 16
    float* __restrict__ ego,
    float* __restrict__ outp,
    int nrows, int node_base)
{
    __shared__ float Wt[DD * WT_S];     // Wt[c][k'] = W1[k][c], k' = k ^ (4*(c>>2))
    __shared__ float W2s[DD * 16];

    for (int i = threadIdx.x; i < TXT * DD; i += 256) {
        int k = i >> 5;
        int c = i & 31;
        Wt[c * WT_S + (k ^ ((c >> 2) << 2))] = W1[i];
    }
    for (int i = threadIdx.x; i < DD * 16; i += 256) W2s[i] = W2[i];
    __syncthreads();

    const int cg = threadIdx.x & 7;
    const int r  = threadIdx.x >> 3;
    const int kx = cg << 2;
    const float* wp0 = &Wt[(cg * 4 + 0) * WT_S];
    const float* wp1 = &Wt[(cg * 4 + 1) * WT_S];
    const float* wp2 = &Wt[(cg * 4 + 2) * WT_S];
    const float* wp3 = &Wt[(cg * 4 + 3) * WT_S];

    const int ntiles = nrows / 32;  // 3125, exact
    for (int tile = blockIdx.x; tile < ntiles; tile += gridDim.x) {
        const int row = tile * 32 + r;
        const float* xrow = X + (size_t)row * TXT;
        float a0 = 0.f, a1 = 0.f, a2 = 0.f, a3 = 0.f;
        #pragma unroll 8
        for (int k = 0; k < TXT; k += 4) {
            const float4 xv = *(const float4*)(xrow + k);
            const int kk = k ^ kx;
            const float4 wa = *(const float4*)(wp0 + kk);
            const float4 wb = *(const float4*)(wp1 + kk);
            const float4 wc = *(const float4*)(wp2 + kk);
            const float4 wd = *(const float4*)(wp3 + kk);
            a0 += xv.x * wa.x + xv.y * wa.y + xv.z * wa.z + xv.w * wa.w;
            a1 += xv.x * wb.x + xv.y * wb.y + xv.z * wb.z + xv.w * wb.w;
            a2 += xv.x * wc.x + xv.y * wc.y + xv.z * wc.z + xv.w * wc.w;
            a3 += xv.x * wd.x + xv.y * wd.y + xv.z * wd.z + xv.w * wd.w;
        }
        a0 = fmaxf(a0, 0.f); a1 = fmaxf(a1, 0.f);
        a2 = fmaxf(a2, 0.f); a3 = fmaxf(a3, 0.f);

        // partial second matmul: this lane owns h cols cg*4 .. cg*4+3
        float p[16];
        #pragma unroll
        for (int j = 0; j < 16; ++j) {
            p[j] = a0 * W2s[(cg * 4 + 0) * 16 + j]
                 + a1 * W2s[(cg * 4 + 1) * 16 + j]
                 + a2 * W2s[(cg * 4 + 2) * 16 + j]
                 + a3 * W2s[(cg * 4 + 3) * 16 + j];
        }
        // butterfly-reduce across the 8 col-groups (lane bits 0..2)
        #pragma unroll
        for (int m = 1; m <= 4; m <<= 1) {
            #pragma unroll
            for (int j = 0; j < 16; ++j) p[j] += __shfl_xor(p[j], m, 64);
        }

        const int node = node_base + row;
        if (cg < 4) {
            float4 v = make_float4(p[cg * 4 + 0], p[cg * 4 + 1],
                                   p[cg * 4 + 2], p[cg * 4 + 3]);
            *(float4*)(ego  + (size_t)node * 32  + 16 + cg * 4) = v;
            *(float4*)(outp + (size_t)node * 128 + 16 + cg * 4) = v;
        }
    }
}

// ---------------------------------------------------------------------------
// side[row] += adj * ego[col]  (scatter-add, 8 threads per edge, 4 dims each)
// ---------------------------------------------------------------------------
__global__ __launch_bounds__(256) void scatter_kernel(
    const int* __restrict__ erow, const int* __restrict__ ecol,
    const float* __restrict__ eval, const float* __restrict__ ego,
    float* __restrict__ side)
{
    int i = blockIdx.x * 256 + threadIdx.x;
    if (i >= NE * 8) return;
    int e = i >> 3, q = i & 7;
    int rI = erow[e];
    int c  = ecol[e];
    float a = eval[e];
    float4 v = ((const float4*)ego)[(size_t)c * 8 + q];
    float* dst = side + (size_t)rI * 32 + q * 4;
    atomicAdd(dst + 0, a * v.x);
    atomicAdd(dst + 1, a * v.y);
    atomicAdd(dst + 2, a * v.z);
    atomicAdd(dst + 3, a * v.w);
}

// ---------------------------------------------------------------------------
// ego = lrelu(side@gcW + gcb) + lrelu((ego*side)@biW + bib); out = normalize
// Thread per node; W via scalar (uniform) loads.
// ---------------------------------------------------------------------------
__global__ __launch_bounds__(256) void update_kernel(
    const float* __restrict__ side, float* __restrict__ ego,
    float* __restrict__ outp,
    const float* __restrict__ gcW, const float* __restrict__ gcb,
    const float* __restrict__ biW, const float* __restrict__ bib, int l)
{
    int n = blockIdx.x * 256 + threadIdx.x;
    if (n >= NN) return;

    float s[32], e[32];
    const float4* s4 = (const float4*)side + (size_t)n * 8;
    const float4* e4 = (const float4*)ego  + (size_t)n * 8;
    #pragma unroll
    for (int q = 0; q < 8; ++q) {
        float4 v = s4[q];
        s[q * 4 + 0] = v.x; s[q * 4 + 1] = v.y; s[q * 4 + 2] = v.z; s[q * 4 + 3] = v.w;
        float4 w = e4[q];
        e[q * 4 + 0] = w.x; e[q * 4 + 1] = w.y; e[q * 4 + 2] = w.z; e[q * 4 + 3] = w.w;
    }
    #pragma unroll
    for (int k = 0; k < 32; ++k) e[k] *= s[k];   // e now holds ego*side

    const float* Wg = gcW + (size_t)l * 1024;
    const float* Wb = biW + (size_t)l * 1024;

    float A[32];
    #pragma unroll
    for (int j = 0; j < 32; ++j) A[j] = gcb[l * 32 + j];
    #pragma unroll 4
    for (int k = 0; k < 32; ++k) {
        float sk = s[k];
        #pragma unroll
        for (int j = 0; j < 32; ++j) A[j] += sk * Wg[k * 32 + j];
    }
    #pragma unroll
    for (int j = 0; j < 32; ++j) A[j] = lrelu(A[j]);

    float B[32];
    #pragma unroll
    for (int j = 0; j < 32; ++j) B[j] = bib[l * 32 + j];
    #pragma unroll 4
    for (int k = 0; k < 32; ++k) {
        float pk = e[k];
        #pragma unroll
        for (int j = 0; j < 32; ++j) B[j] += pk * Wb[k * 32 + j];
    }

    float ss = 0.f;
    #pragma unroll
    for (int j = 0; j < 32; ++j) {
        float v = A[j] + lrelu(B[j]);
        A[j] = v;
        ss += v * v;
    }
    float inv = 1.0f / fmaxf(sqrtf(ss), 1e-12f);

    float4* egod = (float4*)(ego + (size_t)n * 32);
    float4* outd = (float4*)(outp + (size_t)n * 128 + (size_t)(l + 1) * 32);
    #pragma unroll
    for (int q = 0; q < 8; ++q) {
        float4 v = make_float4(A[q * 4 + 0], A[q * 4 + 1], A[q * 4 + 2], A[q * 4 + 3]);
        egod[q] = v;
        float4 w = make_float4(v.x * inv, v.y * inv, v.z * inv, v.w * inv);
        outd[q] = w;
    }
}

// ---------------------------------------------------------------------------
extern "C" void kernel_launch(void* const* d_in, const int* in_sizes, int n_in,
                              void* d_out, int out_size, void* d_ws, size_t ws_size,
                              hipStream_t stream)
{
    const int*   erow = (const int*)d_in[0];
    const int*   ecol = (const int*)d_in[1];
    const float* evalp = (const float*)d_in[2];
    const float* une  = (const float*)d_in[3];
    const float* se   = (const float*)d_in[4];
    const float* uemb = (const float*)d_in[5];
    const float* iemb = (const float*)d_in[6];
    const float* ueW1 = (const float*)d_in[7];
    const float* ueW2 = (const float*)d_in[8];
    const float* ieW1 = (const float*)d_in[9];
    const float* ieW2 = (const float*)d_in[10];
    const float* gcW  = (const float*)d_in[11];
    const float* gcb  = (const float*)d_in[12];
    const float* biW  = (const float*)d_in[13];
    const float* bib  = (const float*)d_in[14];
    float* outp = (float*)d_out;

    float* ego  = (float*)d_ws;                    // NN*32 f32 = 25.6 MB
    float* side = ego + (size_t)NN * 32;           // NN*32 f32 = 25.6 MB

    copy_emb_kernel<<<(NN * 4 + 255) / 256, 256, 0, stream>>>(uemb, iemb, ego, outp);
    mlp_kernel<<<256, 256, 0, stream>>>(une, ueW1, ueW2, ego, outp, NU, 0);
    mlp_kernel<<<256, 256, 0, stream>>>(se, ieW1, ieW2, ego, outp, NI, NU);

    for (int l = 0; l < 3; ++l) {
        hipMemsetAsync(side, 0, (size_t)NN * 32 * sizeof(float), stream);
        scatter_kernel<<<(NE * 8 + 255) / 256, 256, 0, stream>>>(erow, ecol, evalp, ego, side);
        update_kernel<<<(NN + 255) / 256, 256, 0, stream>>>(side, ego, outp,
                                                            gcW, gcb, biW, bib, l);
    }
}

// Round 2
// 1172.099 us; speedup vs baseline: 4.2300x; 4.2300x over previous
//
#include <hip/hip_runtime.h>
#include <cstdint>

#define NU 100000
#define NI 100000
#define NN 200000
#define NE 3200000
#define TXT 768
#define DD 32
#define WT_S 772   // LDS row stride for W1^T (floats)

__device__ __forceinline__ float lrelu(float x) { return x >= 0.f ? x : 0.01f * x; }

// ---------------------------------------------------------------------------
// Copy pretrained 16-dim embeddings into ego[:,0:16] and out[:,0:16]
// ---------------------------------------------------------------------------
__global__ void copy_emb_kernel(const float* __restrict__ uemb,
                                const float* __restrict__ iemb,
                                float* __restrict__ ego,
                                float* __restrict__ outp)
{
    int idx = blockIdx.x * blockDim.x + threadIdx.x;  // over NN*4 float4s
    if (idx >= NN * 4) return;
    int n = idx >> 2, q = idx & 3;
    float4 v;
    if (n < NU) v = ((const float4*)uemb)[(size_t)n * 4 + q];
    else        v = ((const float4*)iemb)[(size_t)(n - NU) * 4 + q];
    ((float4*)ego)[(size_t)n * 8 + q]   = v;
    ((float4*)outp)[(size_t)n * 32 + q] = v;
}

// ---------------------------------------------------------------------------
// created = relu(X @ W1) @ W2 ; writes ego[:,16:32] and out[:,16:32]
// 512 threads, 2 rows/thread (128-row tiles) for deeper VMEM pipelining.
// W1^T staged in LDS (XOR swizzle, conflict-free); W2 rows in registers.
// ---------------------------------------------------------------------------
__global__ __launch_bounds__(512) void mlp_kernel(
    const float* __restrict__ X,    // nrows x 768
    const float* __restrict__ W1,   // 768 x 32
    const float* __restrict__ W2,   // 32 x 16
    float* __restrict__ ego,
    float* __restrict__ outp,
    int nrows, int node_base)
{
    __shared__ float Wt[DD * WT_S];     // Wt[c][k'] = W1[k][c], k' = k ^ (4*(c>>2))

    for (int i = threadIdx.x; i < TXT * DD; i += 512) {
        int k = i >> 5;
        int c = i & 31;
        Wt[c * WT_S + (k ^ ((c >> 2) << 2))] = W1[i];
    }

    const int cg = threadIdx.x & 7;   // col group: owns h cols cg*4..cg*4+3
    const int r  = threadIdx.x >> 3;  // 0..63
    const int kx = cg << 2;

    // W2 rows this lane needs, hoisted to registers (avoids LDS conflicts)
    float w2r[4][16];
    #pragma unroll
    for (int c = 0; c < 4; ++c)
        #pragma unroll
        for (int j = 0; j < 16; ++j)
            w2r[c][j] = W2[(cg * 4 + c) * 16 + j];

    __syncthreads();

    const float* wp0 = &Wt[(cg * 4 + 0) * WT_S];
    const float* wp1 = &Wt[(cg * 4 + 1) * WT_S];
    const float* wp2 = &Wt[(cg * 4 + 2) * WT_S];
    const float* wp3 = &Wt[(cg * 4 + 3) * WT_S];

    const int ntiles = (nrows + 127) / 128;
    for (int tile = blockIdx.x; tile < ntiles; tile += gridDim.x) {
        const int row0 = tile * 128 + r;
        const int row1 = row0 + 64;
        const bool ok0 = row0 < nrows, ok1 = row1 < nrows;
        const float* x0 = X + (size_t)(ok0 ? row0 : 0) * TXT;
        const float* x1 = X + (size_t)(ok1 ? row1 : 0) * TXT;

        float a[2][4] = {{0.f,0.f,0.f,0.f},{0.f,0.f,0.f,0.f}};
        #pragma unroll 4
        for (int k = 0; k < TXT; k += 4) {
            const float4 xa = *(const float4*)(x0 + k);
            const float4 xb = *(const float4*)(x1 + k);
            const int kk = k ^ kx;
            const float4 wa = *(const float4*)(wp0 + kk);
            const float4 wb = *(const float4*)(wp1 + kk);
            const float4 wc = *(const float4*)(wp2 + kk);
            const float4 wd = *(const float4*)(wp3 + kk);
            a[0][0] += xa.x*wa.x + xa.y*wa.y + xa.z*wa.z + xa.w*wa.w;
            a[0][1] += xa.x*wb.x + xa.y*wb.y + xa.z*wb.z + xa.w*wb.w;
            a[0][2] += xa.x*wc.x + xa.y*wc.y + xa.z*wc.z + xa.w*wc.w;
            a[0][3] += xa.x*wd.x + xa.y*wd.y + xa.z*wd.z + xa.w*wd.w;
            a[1][0] += xb.x*wa.x + xb.y*wa.y + xb.z*wa.z + xb.w*wa.w;
            a[1][1] += xb.x*wb.x + xb.y*wb.y + xb.z*wb.z + xb.w*wb.w;
            a[1][2] += xb.x*wc.x + xb.y*wc.y + xb.z*wc.z + xb.w*wc.w;
            a[1][3] += xb.x*wd.x + xb.y*wd.y + xb.z*wd.z + xb.w*wd.w;
        }

        #pragma unroll
        for (int rr = 0; rr < 2; ++rr) {
            float h0 = fmaxf(a[rr][0], 0.f), h1 = fmaxf(a[rr][1], 0.f);
            float h2 = fmaxf(a[rr][2], 0.f), h3 = fmaxf(a[rr][3], 0.f);
            float p[16];
            #pragma unroll
            for (int j = 0; j < 16; ++j)
                p[j] = h0 * w2r[0][j] + h1 * w2r[1][j] + h2 * w2r[2][j] + h3 * w2r[3][j];
            #pragma unroll
            for (int m = 1; m <= 4; m <<= 1) {
                #pragma unroll
                for (int j = 0; j < 16; ++j) p[j] += __shfl_xor(p[j], m, 64);
            }
            const int row = rr ? row1 : row0;
            const bool ok = rr ? ok1 : ok0;
            if (ok && cg < 4) {
                const int node = node_base + row;
                float4 v = make_float4(p[cg*4+0], p[cg*4+1], p[cg*4+2], p[cg*4+3]);
                *(float4*)(ego  + (size_t)node * 32  + 16 + cg * 4) = v;
                *(float4*)(outp + (size_t)node * 128 + 16 + cg * 4) = v;
            }
        }
    }
}

// ---------------------------------------------------------------------------
// CSR build: count -> block scan -> block-sum scan -> add offsets -> fill
// ---------------------------------------------------------------------------
__global__ __launch_bounds__(256) void count_kernel(const int* __restrict__ erow,
                                                    int* __restrict__ cnt)
{
    int e = blockIdx.x * 256 + threadIdx.x;
    if (e < NE) atomicAdd(&cnt[erow[e]], 1);
}

__global__ __launch_bounds__(256) void scan_blk_kernel(const int* __restrict__ cnt,
                                                       int* __restrict__ rp,
                                                       int* __restrict__ bsum)
{
    __shared__ int ts[256];
    const int tid = threadIdx.x;
    const int base = blockIdx.x * 1024 + tid * 4;
    int v0 = (base + 0 < NN) ? cnt[base + 0] : 0;
    int v1 = (base + 1 < NN) ? cnt[base + 1] : 0;
    int v2 = (base + 2 < NN) ? cnt[base + 2] : 0;
    int v3 = (base + 3 < NN) ? cnt[base + 3] : 0;
    int s = v0 + v1 + v2 + v3;
    ts[tid] = s;
    __syncthreads();
    for (int off = 1; off < 256; off <<= 1) {
        int t = (tid >= off) ? ts[tid - off] : 0;
        __syncthreads();
        ts[tid] += t;
        __syncthreads();
    }
    int excl = ts[tid] - s;
    if (base + 0 < NN) rp[base + 0] = excl;
    if (base + 1 < NN) rp[base + 1] = excl + v0;
    if (base + 2 < NN) rp[base + 2] = excl + v0 + v1;
    if (base + 3 < NN) rp[base + 3] = excl + v0 + v1 + v2;
    if (tid == 255) bsum[blockIdx.x] = ts[255];
}

__global__ __launch_bounds__(256) void scan_bsum_kernel(int* __restrict__ bsum, int nblk)
{
    __shared__ int ts[256];
    const int tid = threadIdx.x;
    int v = (tid < nblk) ? bsum[tid] : 0;
    ts[tid] = v;
    __syncthreads();
    for (int off = 1; off < 256; off <<= 1) {
        int t = (tid >= off) ? ts[tid - off] : 0;
        __syncthreads();
        ts[tid] += t;
        __syncthreads();
    }
    if (tid < nblk) bsum[tid] = ts[tid] - v;
}

__global__ __launch_bounds__(256) void add_off_kernel(int* __restrict__ rp,
                                                      const int* __restrict__ bsum,
                                                      int* __restrict__ cur)
{
    int i = blockIdx.x * 256 + threadIdx.x;
    if (i < NN) {
        int v = rp[i] + bsum[i >> 10];
        rp[i] = v;
        cur[i] = v;
    }
    if (i == 0) rp[NN] = NE;
}

__global__ __launch_bounds__(256) void fill_kernel(const int* __restrict__ erow,
                                                   const int* __restrict__ ecol,
                                                   const float* __restrict__ eval,
                                                   int* __restrict__ cur,
                                                   uint2* __restrict__ recs)
{
    int e = blockIdx.x * 256 + threadIdx.x;
    if (e >= NE) return;
    int rI = erow[e];
    int pos = atomicAdd(&cur[rI], 1);
    recs[pos] = make_uint2((unsigned)ecol[e], __float_as_uint(eval[e]));
}

// ---------------------------------------------------------------------------
// Pull aggregation: one wave per row; 8 edge-slots x 8 dim-lanes; no atomics.
// ---------------------------------------------------------------------------
__global__ __launch_bounds__(256) void pull_kernel(
    const int* __restrict__ rp, const uint2* __restrict__ recs,
    const float* __restrict__ ego, float* __restrict__ side)
{
    const int w    = blockIdx.x * 4 + (threadIdx.x >> 6);   // row
    const int lane = threadIdx.x & 63;
    const int slot = lane >> 3;   // edge slot 0..7
    const int q    = lane & 7;    // float4 index 0..7 (dims q*4..q*4+3)
    const int start = rp[w], end = rp[w + 1];

    float4 acc = make_float4(0.f, 0.f, 0.f, 0.f);
    for (int e = start + slot; e < end; e += 8) {
        uint2 rec = recs[e];
        float a = __uint_as_float(rec.y);
        float4 v = ((const float4*)ego)[(size_t)rec.x * 8 + q];
        acc.x += a * v.x; acc.y += a * v.y; acc.z += a * v.z; acc.w += a * v.w;
    }
    #pragma unroll
    for (int m = 8; m <= 32; m <<= 1) {
        acc.x += __shfl_xor(acc.x, m, 64);
        acc.y += __shfl_xor(acc.y, m, 64);
        acc.z += __shfl_xor(acc.z, m, 64);
        acc.w += __shfl_xor(acc.w, m, 64);
    }
    if (slot == 0)
        ((float4*)side)[(size_t)w * 8 + q] = acc;
}

// ---------------------------------------------------------------------------
// Legacy scatter (fallback if workspace too small for CSR)
// ---------------------------------------------------------------------------
__global__ __launch_bounds__(256) void scatter_kernel(
    const int* __restrict__ erow, const int* __restrict__ ecol,
    const float* __restrict__ eval, const float* __restrict__ ego,
    float* __restrict__ side)
{
    int i = blockIdx.x * 256 + threadIdx.x;
    if (i >= NE * 8) return;
    int e = i >> 3, q = i & 7;
    int rI = erow[e];
    int c  = ecol[e];
    float a = eval[e];
    float4 v = ((const float4*)ego)[(size_t)c * 8 + q];
    float* dst = side + (size_t)rI * 32 + q * 4;
    atomicAdd(dst + 0, a * v.x);
    atomicAdd(dst + 1, a * v.y);
    atomicAdd(dst + 2, a * v.z);
    atomicAdd(dst + 3, a * v.w);
}

// ---------------------------------------------------------------------------
// ego = lrelu(side@gcW + gcb) + lrelu((ego*side)@biW + bib); out = normalize
// ---------------------------------------------------------------------------
__global__ __launch_bounds__(256) void update_kernel(
    const float* __restrict__ side, float* __restrict__ ego,
    float* __restrict__ outp,
    const float* __restrict__ gcW, const float* __restrict__ gcb,
    const float* __restrict__ biW, const float* __restrict__ bib, int l)
{
    int n = blockIdx.x * 256 + threadIdx.x;
    if (n >= NN) return;

    float s[32], e[32];
    const float4* s4 = (const float4*)side + (size_t)n * 8;
    const float4* e4 = (const float4*)ego  + (size_t)n * 8;
    #pragma unroll
    for (int q = 0; q < 8; ++q) {
        float4 v = s4[q];
        s[q*4+0] = v.x; s[q*4+1] = v.y; s[q*4+2] = v.z; s[q*4+3] = v.w;
        float4 w = e4[q];
        e[q*4+0] = w.x; e[q*4+1] = w.y; e[q*4+2] = w.z; e[q*4+3] = w.w;
    }
    #pragma unroll
    for (int k = 0; k < 32; ++k) e[k] *= s[k];

    const float* Wg = gcW + (size_t)l * 1024;
    const float* Wb = biW + (size_t)l * 1024;

    float A[32];
    #pragma unroll
    for (int j = 0; j < 32; ++j) A[j] = gcb[l * 32 + j];
    #pragma unroll 4
    for (int k = 0; k < 32; ++k) {
        float sk = s[k];
        #pragma unroll
        for (int j = 0; j < 32; ++j) A[j] += sk * Wg[k * 32 + j];
    }
    #pragma unroll
    for (int j = 0; j < 32; ++j) A[j] = lrelu(A[j]);

    float B[32];
    #pragma unroll
    for (int j = 0; j < 32; ++j) B[j] = bib[l * 32 + j];
    #pragma unroll 4
    for (int k = 0; k < 32; ++k) {
        float pk = e[k];
        #pragma unroll
        for (int j = 0; j < 32; ++j) B[j] += pk * Wb[k * 32 + j];
    }

    float ss = 0.f;
    #pragma unroll
    for (int j = 0; j < 32; ++j) {
        float v = A[j] + lrelu(B[j]);
        A[j] = v;
        ss += v * v;
    }
    float inv = 1.0f / fmaxf(sqrtf(ss), 1e-12f);

    float4* egod = (float4*)(ego + (size_t)n * 32);
    float4* outd = (float4*)(outp + (size_t)n * 128 + (size_t)(l + 1) * 32);
    #pragma unroll
    for (int q = 0; q < 8; ++q) {
        float4 v = make_float4(A[q*4+0], A[q*4+1], A[q*4+2], A[q*4+3]);
        egod[q] = v;
        float4 w = make_float4(v.x*inv, v.y*inv, v.z*inv, v.w*inv);
        outd[q] = w;
    }
}

// ---------------------------------------------------------------------------
extern "C" void kernel_launch(void* const* d_in, const int* in_sizes, int n_in,
                              void* d_out, int out_size, void* d_ws, size_t ws_size,
                              hipStream_t stream)
{
    const int*   erow = (const int*)d_in[0];
    const int*   ecol = (const int*)d_in[1];
    const float* evalp = (const float*)d_in[2];
    const float* une  = (const float*)d_in[3];
    const float* se   = (const float*)d_in[4];
    const float* uemb = (const float*)d_in[5];
    const float* iemb = (const float*)d_in[6];
    const float* ueW1 = (const float*)d_in[7];
    const float* ueW2 = (const float*)d_in[8];
    const float* ieW1 = (const float*)d_in[9];
    const float* ieW2 = (const float*)d_in[10];
    const float* gcW  = (const float*)d_in[11];
    const float* gcb  = (const float*)d_in[12];
    const float* biW  = (const float*)d_in[13];
    const float* bib  = (const float*)d_in[14];
    float* outp = (float*)d_out;

    float* ego  = (float*)d_ws;                        // NN*32 f32
    float* side = ego + (size_t)NN * 32;               // NN*32 f32
    uint2* recs = (uint2*)(side + (size_t)NN * 32);    // NE uint2
    int*   cnt  = (int*)(recs + (size_t)NE);           // NN
    int*   rp   = cnt + NN;                            // NN+1
    int*   cur  = rp + NN + 1;                         // NN
    int*   bsum = cur + NN;                            // 256

    const size_t need = (size_t)(bsum + 256) - (size_t)d_ws;
    const bool csr_ok = ws_size >= need;

    copy_emb_kernel<<<(NN * 4 + 255) / 256, 256, 0, stream>>>(uemb, iemb, ego, outp);
    mlp_kernel<<<782, 512, 0, stream>>>(une, ueW1, ueW2, ego, outp, NU, 0);
    mlp_kernel<<<782, 512, 0, stream>>>(se, ieW1, ieW2, ego, outp, NI, NU);

    if (csr_ok) {
        const int NBLK = (NN + 1023) / 1024;  // 196
        hipMemsetAsync(cnt, 0, (size_t)NN * sizeof(int), stream);
        count_kernel<<<(NE + 255) / 256, 256, 0, stream>>>(erow, cnt);
        scan_blk_kernel<<<NBLK, 256, 0, stream>>>(cnt, rp, bsum);
        scan_bsum_kernel<<<1, 256, 0, stream>>>(bsum, NBLK);
        add_off_kernel<<<(NN + 255) / 256, 256, 0, stream>>>(rp, bsum, cur);
        fill_kernel<<<(NE + 255) / 256, 256, 0, stream>>>(erow, ecol, evalp, cur, recs);

        for (int l = 0; l < 3; ++l) {
            pull_kernel<<<NN / 4, 256, 0, stream>>>(rp, recs, ego, side);
            update_kernel<<<(NN + 255) / 256, 256, 0, stream>>>(side, ego, outp,
                                                                gcW, gcb, biW, bib, l);
        }
    } else {
        for (int l = 0; l < 3; ++l) {
            hipMemsetAsync(side, 0, (size_t)NN * 32 * sizeof(float), stream);
            scatter_kernel<<<(NE * 8 + 255) / 256, 256, 0, stream>>>(erow, ecol, evalp, ego, side);
            update_kernel<<<(NN + 255) / 256, 256, 0, stream>>>(side, ego, outp,
                                                                gcW, gcb, biW, bib, l);
        }
    }
}